// Round 6
// baseline (748.570 us; speedup 1.0000x reference)
//
#include <hip/hip_runtime.h>
#include <hip/hip_bf16.h>
#include <stdint.h>

#define N_NODES 50000
#define N_EDGES 800000
#define NBK 8                    // src buckets
#define BUCK 6250                // rows per bucket (50000/8)
#define NC2 400000               // (dst,bucket) counters
#define NB2 1563                 // ceil(400000/256)

typedef __attribute__((ext_vector_type(8))) short short8;
typedef __attribute__((ext_vector_type(4))) float floatx4;

__device__ __forceinline__ float bfbits2f(unsigned int u16) {
    union { unsigned int i; float f; } c; c.i = u16 << 16; return c.f;
}
__device__ __forceinline__ unsigned short f2bfbits(float f) {
    union { float f; unsigned int i; } c; c.f = f;
    unsigned int r = c.i + 0x7fffu + ((c.i >> 16) & 1u);   // RNE
    return (unsigned short)(r >> 16);
}
__device__ __forceinline__ void acc8(float* a, uint4 v) {
    a[0] += bfbits2f(v.x & 0xffffu); a[1] += bfbits2f(v.x >> 16);
    a[2] += bfbits2f(v.y & 0xffffu); a[3] += bfbits2f(v.y >> 16);
    a[4] += bfbits2f(v.z & 0xffffu); a[5] += bfbits2f(v.z >> 16);
    a[6] += bfbits2f(v.w & 0xffffu); a[7] += bfbits2f(v.w >> 16);
}

// ---------------- dtype detection (1 block) — verified r2, DO NOT TOUCH ----------------
__global__ __launch_bounds__(256) void detect(
    const unsigned short* __restrict__ x16, const int* __restrict__ e,
    int* __restrict__ flags)
{
    __shared__ int s_cnt[2];
    const int t = threadIdx.x;
    if (t < 2) s_cnt[t] = 0;
    __syncthreads();
    unsigned short v = x16[2 * t];
    int ex = (v >> 7) & 0xff;
    if (v == 0 || (ex >= 96 && ex <= 150)) atomicAdd(&s_cnt[0], 1);
    if (e[2 * t + 1] != 0) atomicAdd(&s_cnt[1], 1);
    __syncthreads();
    if (t == 0) {
        flags[0] = (s_cnt[0] < 200) ? 1 : 0;
        flags[1] = (s_cnt[1] < 128) ? 1 : 0;
    }
}

// ---------------- merged weight/bias prep (verified r4) ----------------
__global__ __launch_bounds__(256) void prep_all(
    const void* __restrict__ Wl0, const void* __restrict__ Wr0,
    const void* __restrict__ Wl1, const void* __restrict__ Wr1,
    const void* __restrict__ Wl2, const void* __restrict__ Wr2,
    const void* __restrict__ b0, const void* __restrict__ b1, const void* __restrict__ b2,
    unsigned short* __restrict__ wt, const int* __restrict__ flags)
{
    const int bid = blockIdx.x, t = threadIdx.x;
    const int f = flags[0];
    if (bid >= 1024) {                       // biases
        const void* bs = bid == 1024 ? b0 : (bid == 1025 ? b1 : b2);
        unsigned short* bd = wt + 262144 + (bid - 1024) * 256;
        int n = (bid == 1026) ? 128 : 256;
        if (t < n) bd[t] = f ? f2bfbits(((const float*)bs)[t]) : ((const unsigned short*)bs)[t];
        return;
    }
    const void* W; unsigned short* WT; int K, N, off;
    if (bid < 128)      { W = Wl0; WT = wt;          K = 128; N = 256; off = bid; }
    else if (bid < 256) { W = Wr0; WT = wt + 32768;  K = 128; N = 256; off = bid - 128; }
    else if (bid < 512) { W = Wl1; WT = wt + 65536;  K = 256; N = 256; off = bid - 256; }
    else if (bid < 768) { W = Wr1; WT = wt + 131072; K = 256; N = 256; off = bid - 512; }
    else if (bid < 896) { W = Wl2; WT = wt + 196608; K = 256; N = 128; off = bid - 768; }
    else                { W = Wr2; WT = wt + 229376; K = 256; N = 128; off = bid - 896; }
    int idx = off * 256 + t;
    int k = idx / N, n = idx - k * N;
    unsigned short v = f ? f2bfbits(((const float*)W)[idx]) : ((const unsigned short*)W)[idx];
    WT[n * K + k] = v;
}

// ---------------- x -> bf16 ----------------
__global__ __launch_bounds__(256) void cvt_x(
    const void* __restrict__ x, unsigned short* __restrict__ xb,
    const int* __restrict__ flags)
{
    int i = blockIdx.x * 256 + threadIdx.x;
    if (flags[0]) {
        float4 v = ((const float4*)x)[i];
        uint2 o;
        o.x = (unsigned int)f2bfbits(v.x) | ((unsigned int)f2bfbits(v.y) << 16);
        o.y = (unsigned int)f2bfbits(v.z) | ((unsigned int)f2bfbits(v.w) << 16);
        ((uint2*)xb)[i] = o;
    } else {
        ((uint2*)xb)[i] = ((const uint2*)x)[i];
    }
}

// ---------------- bucketed CSR build: counters at (dst*8 + src/BUCK) ----------------
__global__ __launch_bounds__(256) void zero2(int* __restrict__ c) {
    int i = blockIdx.x * 256 + threadIdx.x;
    if (i < NC2) c[i] = 0;
}

__global__ __launch_bounds__(256) void edge_count2(
    const int* __restrict__ e, int* __restrict__ cnt2, const int* __restrict__ flags)
{
    int i = blockIdx.x * 256 + threadIdx.x;
    int f = flags[1];
    int src = f ? e[2 * i] : e[i];
    int dst = f ? e[2 * (N_EDGES + i)] : e[N_EDGES + i];
    atomicAdd(&cnt2[dst * NBK + src / BUCK], 1);
}

// in-place local exclusive scan over 400k counters (tile=256), totals -> part[]
__global__ __launch_bounds__(256) void scan_k1b(
    int* __restrict__ rp2, int* __restrict__ part)
{
    __shared__ int sa[256], sb[256];
    const int b = blockIdx.x, t = threadIdx.x, idx = b * 256 + t;
    int v = (idx < NC2) ? rp2[idx] : 0;
    sa[t] = v;
    __syncthreads();
    bool par = true;
#pragma unroll
    for (int off = 1; off < 256; off <<= 1) {
        if (par) { int x = sa[t] + (t >= off ? sa[t - off] : 0); sb[t] = x; }
        else     { int x = sb[t] + (t >= off ? sb[t - off] : 0); sa[t] = x; }
        par = !par;
        __syncthreads();
    }
    if (idx < NC2) rp2[idx] = sa[t] - v;
    if (t == 255) part[b] = sa[255];
}

// exclusive-scan the NB2=1563 tile totals (1 block, looped — r2-verified pattern)
__global__ __launch_bounds__(256) void scan_k2b(int* __restrict__ part) {
    __shared__ int sa[256], sb[256];
    const int t = threadIdx.x;
    int run = 0;
    for (int j = 0; j < NB2; j += 256) {
        const int idx = j + t;
        int v = (idx < NB2) ? part[idx] : 0;
        sa[t] = v;
        __syncthreads();
        bool par = true;
#pragma unroll
        for (int off = 1; off < 256; off <<= 1) {
            if (par) { int x = sa[t] + (t >= off ? sa[t - off] : 0); sb[t] = x; }
            else     { int x = sb[t] + (t >= off ? sb[t - off] : 0); sa[t] = x; }
            par = !par;
            __syncthreads();
        }
        if (idx < NB2) part[idx] = run + sa[t] - v;   // exclusive
        run += sa[255];
        __syncthreads();
    }
}

__global__ __launch_bounds__(256) void scan_k3b(
    int* __restrict__ rp2, const int* __restrict__ part, int* __restrict__ cur2)
{
    const int b = blockIdx.x, idx = b * 256 + threadIdx.x;
    if (idx < NC2) {
        int v = rp2[idx] + part[b];
        rp2[idx] = v;
        cur2[idx] = v;
    } else if (idx == NC2) {
        rp2[idx] = N_EDGES;                           // sentinel
    }
}

__global__ __launch_bounds__(256) void edge_fill2(
    const int* __restrict__ e, int* __restrict__ cur2, int* __restrict__ csr,
    const int* __restrict__ flags)
{
    int i = blockIdx.x * 256 + threadIdx.x;
    int f = flags[1];
    int src = f ? e[2 * i] : e[i];
    int dst = f ? e[2 * (N_EDGES + i)] : e[N_EDGES + i];
    csr[atomicAdd(&cur2[dst * NBK + src / BUCK], 1)] = src;
}

// ---------------- fused layer (L0/L1) — gather loop byte-identical to r5 ----------------
template<int K>
__global__ __launch_bounds__(256) void sage_fused(
    const unsigned short* __restrict__ hin,   // [N,K] bf16
    const int* __restrict__ rp2,              // (dst,bucket) rowptr, stride NBK per node
    const int* __restrict__ csr_src,
    const unsigned short* __restrict__ WlT,   // [256,K]
    const unsigned short* __restrict__ WrT,   // [256,K]
    const unsigned short* __restrict__ bb,    // [256]
    unsigned short* __restrict__ hout)        // [N,256]
{
    constexpr int CH = K / 8;
    constexpr int CAP = 3072;
    __shared__ unsigned short A0s[16][K + 8];
    __shared__ int sidx[CAP];
    __shared__ int srp[17];
    const int tid = threadIdx.x;
    const int m0 = blockIdx.x * 16;
    if (tid < 17) srp[tid] = rp2[(m0 + tid) * NBK];   // node boundaries = bucket 0
    __syncthreads();
    const int base = srp[0];
    const int total = srp[16] - base;
    const bool staged = total <= CAP;
    if (staged) {
        for (int i = tid; i < total; i += 256) sidx[i] = csr_src[base + i];
    }
    __syncthreads();

    // ---- phase 1: gather + mean (r5-verified) ----
    for (int it = tid; it < 16 * CH; it += 256) {
        const int rr = it / CH;
        const int cc = it & (CH - 1);
        const int beg = srp[rr];
        const int deg = srp[rr + 1] - beg;
        const int begl = beg - base;
        float a[8], g[8];
#pragma unroll
        for (int v = 0; v < 8; ++v) { a[v] = 0.f; g[v] = 0.f; }
        const unsigned short* col = hin + cc * 8;
        auto run = [&](auto IDX) {
            int j = 0;
            for (; j + 3 < deg; j += 4) {
                int s0 = IDX(j), s1 = IDX(j + 1), s2 = IDX(j + 2), s3 = IDX(j + 3);
                uint4 v0 = *(const uint4*)(col + (size_t)s0 * K);
                uint4 v1 = *(const uint4*)(col + (size_t)s1 * K);
                uint4 v2 = *(const uint4*)(col + (size_t)s2 * K);
                uint4 v3 = *(const uint4*)(col + (size_t)s3 * K);
                acc8(a, v0); acc8(g, v1); acc8(a, v2); acc8(g, v3);
            }
            for (; j < deg; ++j) {
                uint4 v0 = *(const uint4*)(col + (size_t)IDX(j) * K);
                acc8(a, v0);
            }
        };
        if (staged) run([&](int j) { return sidx[begl + j]; });
        else        run([&](int j) { return csr_src[beg + j]; });
        const float inv = 1.0f / fmaxf((float)deg, 1.0f);
        short8 t8;
#pragma unroll
        for (int v = 0; v < 8; ++v) t8[v] = (short)f2bfbits((a[v] + g[v]) * inv);
        *(short8*)&A0s[rr][cc * 8] = t8;
    }
    __syncthreads();

    // ---- phase 2: MFMA dual GEMM + bias + relu (r4-verified) ----
    const int lane = tid & 63;
    const int wave = tid >> 6;
    const int r = lane & 15;
    const int quad = lane >> 4;
    short8 a0f[K / 32], a1f[K / 32];
#pragma unroll
    for (int k0 = 0; k0 < K / 32; ++k0)
        a0f[k0] = *(const short8*)&A0s[r][k0 * 32 + quad * 8];
    const unsigned short* hb = hin + (size_t)(m0 + r) * K + quad * 8;
#pragma unroll
    for (int k0 = 0; k0 < K / 32; ++k0)
        a1f[k0] = *(const short8*)(hb + k0 * 32);

    for (int nt = wave; nt < 16; nt += 4) {
        const int n0 = nt * 16;
        floatx4 acc = {0.f, 0.f, 0.f, 0.f};
        const unsigned short* b0 = WlT + (size_t)(n0 + r) * K + quad * 8;
        const unsigned short* b1 = WrT + (size_t)(n0 + r) * K + quad * 8;
#pragma unroll
        for (int k0 = 0; k0 < K / 32; ++k0)
            acc = __builtin_amdgcn_mfma_f32_16x16x32_bf16(a0f[k0], *(const short8*)(b0 + k0 * 32), acc, 0, 0, 0);
#pragma unroll
        for (int k0 = 0; k0 < K / 32; ++k0)
            acc = __builtin_amdgcn_mfma_f32_16x16x32_bf16(a1f[k0], *(const short8*)(b1 + k0 * 32), acc, 0, 0, 0);

        // C/D layout: col = lane&15, row = quad*4 + reg  [HW-verified]
        const int ccol = n0 + r;
        float bv = bfbits2f(bb[ccol]);
#pragma unroll
        for (int i = 0; i < 4; ++i) {
            float v = acc[i] + bv;
            v = v > 0.f ? v : 0.f;
            hout[(size_t)(m0 + quad * 4 + i) * 256 + ccol] = f2bfbits(v);
        }
    }
}

// ---------------- L2 GEMM pair (r5-verified) ----------------
__global__ __launch_bounds__(256) void gemm_pair(
    const unsigned short* __restrict__ A,
    const unsigned short* __restrict__ WT,
    unsigned short* __restrict__ out0,
    unsigned short* __restrict__ out1)
{
    const int tid = threadIdx.x, lane = tid & 63, wave = tid >> 6;
    const int m0 = blockIdx.x * 16;
    const int r = lane & 15, quad = lane >> 4;
    short8 af[8];
    const unsigned short* ab = A + (size_t)(m0 + r) * 256 + quad * 8;
#pragma unroll
    for (int k0 = 0; k0 < 8; ++k0) af[k0] = *(const short8*)(ab + k0 * 32);

    for (int nt = wave; nt < 16; nt += 4) {
        const int n0 = nt * 16;
        floatx4 acc = {0.f, 0.f, 0.f, 0.f};
        const unsigned short* b0 = WT + (size_t)(n0 + r) * 256 + quad * 8;
#pragma unroll
        for (int k0 = 0; k0 < 8; ++k0)
            acc = __builtin_amdgcn_mfma_f32_16x16x32_bf16(af[k0], *(const short8*)(b0 + k0 * 32), acc, 0, 0, 0);
        const int ccol = n0 + r;
#pragma unroll
        for (int i = 0; i < 4; ++i) {
            const size_t row = m0 + quad * 4 + i;
            unsigned short v = f2bfbits(acc[i]);
            if (ccol < 128) out0[row * 128 + ccol] = v;
            else            out1[row * 128 + ccol - 128] = v;
        }
    }
}

// ---------------- L2 aggregate + epilogue (r5-verified; dead init removed) ----------------
__global__ __launch_bounds__(256) void agg2(
    const unsigned short* __restrict__ hl2,
    const unsigned short* __restrict__ hr2,
    const int* __restrict__ rp2,
    const int* __restrict__ csr_src,
    const unsigned short* __restrict__ bb,
    void* __restrict__ out,
    const int* __restrict__ flags)
{
    constexpr int K = 128, CAP = 3072;
    __shared__ int sidx[CAP];
    __shared__ int srp[17];
    const int tid = threadIdx.x;
    const int m0 = blockIdx.x * 16;
    if (tid < 17) srp[tid] = rp2[(m0 + tid) * NBK];
    __syncthreads();
    const int base = srp[0];
    const int total = srp[16] - base;
    const bool staged = total <= CAP;
    if (staged) {
        for (int i = tid; i < total; i += 256) sidx[i] = csr_src[base + i];
    }
    __syncthreads();

    const int rr = tid >> 4;
    const int cc = tid & 15;
    const int beg = srp[rr];
    const int deg = srp[rr + 1] - beg;
    const int begl = beg - base;
    float a[8], g[8];
#pragma unroll
    for (int v = 0; v < 8; ++v) { a[v] = 0.f; g[v] = 0.f; }
    const unsigned short* col = hl2 + cc * 8;
    auto run = [&](auto IDX) {
        int j = 0;
        for (; j + 3 < deg; j += 4) {
            int s0 = IDX(j), s1 = IDX(j + 1), s2 = IDX(j + 2), s3 = IDX(j + 3);
            uint4 v0 = *(const uint4*)(col + (size_t)s0 * K);
            uint4 v1 = *(const uint4*)(col + (size_t)s1 * K);
            uint4 v2 = *(const uint4*)(col + (size_t)s2 * K);
            uint4 v3 = *(const uint4*)(col + (size_t)s3 * K);
            acc8(a, v0); acc8(g, v1); acc8(a, v2); acc8(g, v3);
        }
        for (; j < deg; ++j) {
            uint4 v0 = *(const uint4*)(col + (size_t)IDX(j) * K);
            acc8(a, v0);
        }
    };
    if (staged) run([&](int j) { return sidx[begl + j]; });
    else        run([&](int j) { return csr_src[beg + j]; });

    const float inv = 1.0f / fmaxf((float)deg, 1.0f);
    const size_t ro = (size_t)(m0 + rr) * K + cc * 8;
    uint4 hv = *(const uint4*)(hr2 + ro);
    uint4 bv = *(const uint4*)(bb + cc * 8);
    float h8[8], b8[8];
    h8[0] = bfbits2f(hv.x & 0xffffu); h8[1] = bfbits2f(hv.x >> 16);
    h8[2] = bfbits2f(hv.y & 0xffffu); h8[3] = bfbits2f(hv.y >> 16);
    h8[4] = bfbits2f(hv.z & 0xffffu); h8[5] = bfbits2f(hv.z >> 16);
    h8[6] = bfbits2f(hv.w & 0xffffu); h8[7] = bfbits2f(hv.w >> 16);
    b8[0] = bfbits2f(bv.x & 0xffffu); b8[1] = bfbits2f(bv.x >> 16);
    b8[2] = bfbits2f(bv.y & 0xffffu); b8[3] = bfbits2f(bv.y >> 16);
    b8[4] = bfbits2f(bv.z & 0xffffu); b8[5] = bfbits2f(bv.z >> 16);
    b8[6] = bfbits2f(bv.w & 0xffffu); b8[7] = bfbits2f(bv.w >> 16);
    float o8[8];
#pragma unroll
    for (int v = 0; v < 8; ++v) {
        float m = (a[v] + g[v]) * inv + b8[v] + h8[v];
        o8[v] = m > 0.f ? m : 0.f;
    }
    if (flags[0]) {
        float* op = (float*)out + ro;
        float4 o0 = { o8[0], o8[1], o8[2], o8[3] };
        float4 o1 = { o8[4], o8[5], o8[6], o8[7] };
        *(float4*)op = o0;
        *(float4*)(op + 4) = o1;
    } else {
        short8 t8;
#pragma unroll
        for (int v = 0; v < 8; ++v) t8[v] = (short)f2bfbits(o8[v]);
        *(short8*)((unsigned short*)out + ro) = t8;
    }
}

// ---------------- orchestration ----------------
extern "C" void kernel_launch(void* const* d_in, const int* in_sizes, int n_in,
                              void* d_out, int out_size, void* d_ws, size_t ws_size,
                              hipStream_t stream) {
    const void* x  = d_in[0];
    const int* e[3] = { (const int*)d_in[1], (const int*)d_in[2], (const int*)d_in[3] };

    char* ws = (char*)d_ws;
    int* flags = (int*)ws;                                    // @0
    unsigned short* wt = (unsigned short*)(ws + 1024);        // 525,568 B -> ends 526,592
    unsigned short* bb0 = wt + 262144;
    unsigned short* bb1 = wt + 262400;
    unsigned short* bb2 = wt + 262656;
    int* rp2  = (int*)(ws + 526592);                          // 400,001 ints -> ends 2,126,596
    int* cur2 = (int*)(ws + 2126596);                         // 400,000 ints -> ends 3,726,596
    int* part = (int*)(ws + 3726596);                         // 1,563 ints  -> ends 3,732,848
    int* csr  = (int*)(ws + 3732848);                         // 3.2 MB      -> ends 6,932,848
    unsigned short* hA = (unsigned short*)(ws + 6932848);     // 25.6 MB     -> ends 32,532,848
    unsigned short* hB = (unsigned short*)(ws + 32532848);    // 25.6 MB     -> ends 58,132,848 (58.1 MB)
    // overlays (lifetime-disjoint):
    unsigned short* xb  = hB;                 // dies when L1 fused writes hB
    unsigned short* hl2 = hA;                 // hA dead after L1 fused reads it
    unsigned short* hr2 = hA + (size_t)N_NODES * 128;

    detect<<<1, 256, 0, stream>>>((const unsigned short*)x, e[0], flags);
    prep_all<<<1027, 256, 0, stream>>>(d_in[4], d_in[6], d_in[7], d_in[9],
                                       d_in[10], d_in[12], d_in[5], d_in[8], d_in[11],
                                       wt, flags);
    cvt_x<<<6250, 256, 0, stream>>>(x, xb, flags);

    const int EG = N_EDGES / 256;     // 3125
    const int MG = N_NODES / 16;      // 3125

    auto build_csr = [&](const int* eg) {
        zero2<<<NB2, 256, 0, stream>>>(rp2);
        edge_count2<<<EG, 256, 0, stream>>>(eg, rp2, flags);
        scan_k1b<<<NB2, 256, 0, stream>>>(rp2, part);
        scan_k2b<<<1, 256, 0, stream>>>(part);
        scan_k3b<<<NB2, 256, 0, stream>>>(rp2, part, cur2);
        edge_fill2<<<EG, 256, 0, stream>>>(eg, cur2, csr, flags);
    };

    // ---- layer 0: xb[.,128] -> hA[.,256] ----
    build_csr(e[0]);
    sage_fused<128><<<MG, 256, 0, stream>>>(xb, rp2, csr, wt, wt + 32768, bb0, hA);

    // ---- layer 1: hA[.,256] -> hB[.,256] (clobbers xb — xb dead) ----
    build_csr(e[1]);
    sage_fused<256><<<MG, 256, 0, stream>>>(hA, rp2, csr, wt + 65536, wt + 131072, bb1, hB);

    // ---- layer 2 (reordered): hl2 = hB@Wl2, hr2 = hB@Wr2; out = relu(mean(hl2)+b2+hr2) ----
    build_csr(e[2]);
    gemm_pair<<<MG, 256, 0, stream>>>(hB, wt + 196608, hl2, hr2);   // writes over dead hA
    agg2<<<MG, 256, 0, stream>>>(hl2, hr2, rp2, csr, bb2, d_out, flags);
}

// Round 7
// 711.482 us; speedup vs baseline: 1.0521x; 1.0521x over previous
//
#include <hip/hip_runtime.h>
#include <hip/hip_bf16.h>
#include <stdint.h>

#define N_NODES 50000
#define N_EDGES 800000
#define NC3 150000               // 3 graphs x 50k counters
#define NB3 586                  // ceil(150016/256) tiles covering NC3+sentinel

typedef __attribute__((ext_vector_type(8))) short short8;
typedef __attribute__((ext_vector_type(4))) float floatx4;

__device__ __forceinline__ float bfbits2f(unsigned int u16) {
    union { unsigned int i; float f; } c; c.i = u16 << 16; return c.f;
}
__device__ __forceinline__ unsigned short f2bfbits(float f) {
    union { float f; unsigned int i; } c; c.f = f;
    unsigned int r = c.i + 0x7fffu + ((c.i >> 16) & 1u);   // RNE
    return (unsigned short)(r >> 16);
}
__device__ __forceinline__ void acc8(float* a, uint4 v) {
    a[0] += bfbits2f(v.x & 0xffffu); a[1] += bfbits2f(v.x >> 16);
    a[2] += bfbits2f(v.y & 0xffffu); a[3] += bfbits2f(v.y >> 16);
    a[4] += bfbits2f(v.z & 0xffffu); a[5] += bfbits2f(v.z >> 16);
    a[6] += bfbits2f(v.w & 0xffffu); a[7] += bfbits2f(v.w >> 16);
}

// ---------------- dtype detection (1 block) — verified r2, DO NOT TOUCH ----------------
__global__ __launch_bounds__(256) void detect(
    const unsigned short* __restrict__ x16, const int* __restrict__ e,
    int* __restrict__ flags)
{
    __shared__ int s_cnt[2];
    const int t = threadIdx.x;
    if (t < 2) s_cnt[t] = 0;
    __syncthreads();
    unsigned short v = x16[2 * t];
    int ex = (v >> 7) & 0xff;
    if (v == 0 || (ex >= 96 && ex <= 150)) atomicAdd(&s_cnt[0], 1);
    if (e[2 * t + 1] != 0) atomicAdd(&s_cnt[1], 1);
    __syncthreads();
    if (t == 0) {
        flags[0] = (s_cnt[0] < 200) ? 1 : 0;
        flags[1] = (s_cnt[1] < 128) ? 1 : 0;
    }
}

// ---------------- merged weight/bias prep (verified r4) ----------------
__global__ __launch_bounds__(256) void prep_all(
    const void* __restrict__ Wl0, const void* __restrict__ Wr0,
    const void* __restrict__ Wl1, const void* __restrict__ Wr1,
    const void* __restrict__ Wl2, const void* __restrict__ Wr2,
    const void* __restrict__ b0, const void* __restrict__ b1, const void* __restrict__ b2,
    unsigned short* __restrict__ wt, const int* __restrict__ flags)
{
    const int bid = blockIdx.x, t = threadIdx.x;
    const int f = flags[0];
    if (bid >= 1024) {                       // biases
        const void* bs = bid == 1024 ? b0 : (bid == 1025 ? b1 : b2);
        unsigned short* bd = wt + 262144 + (bid - 1024) * 256;
        int n = (bid == 1026) ? 128 : 256;
        if (t < n) bd[t] = f ? f2bfbits(((const float*)bs)[t]) : ((const unsigned short*)bs)[t];
        return;
    }
    const void* W; unsigned short* WT; int K, N, off;
    if (bid < 128)      { W = Wl0; WT = wt;          K = 128; N = 256; off = bid; }
    else if (bid < 256) { W = Wr0; WT = wt + 32768;  K = 128; N = 256; off = bid - 128; }
    else if (bid < 512) { W = Wl1; WT = wt + 65536;  K = 256; N = 256; off = bid - 256; }
    else if (bid < 768) { W = Wr1; WT = wt + 131072; K = 256; N = 256; off = bid - 512; }
    else if (bid < 896) { W = Wl2; WT = wt + 196608; K = 256; N = 128; off = bid - 768; }
    else                { W = Wr2; WT = wt + 229376; K = 256; N = 128; off = bid - 896; }
    int idx = off * 256 + t;
    int k = idx / N, n = idx - k * N;
    unsigned short v = f ? f2bfbits(((const float*)W)[idx]) : ((const unsigned short*)W)[idx];
    WT[n * K + k] = v;
}

// ---------------- x -> bf16 ----------------
__global__ __launch_bounds__(256) void cvt_x(
    const void* __restrict__ x, unsigned short* __restrict__ xb,
    const int* __restrict__ flags)
{
    int i = blockIdx.x * 256 + threadIdx.x;
    if (flags[0]) {
        float4 v = ((const float4*)x)[i];
        uint2 o;
        o.x = (unsigned int)f2bfbits(v.x) | ((unsigned int)f2bfbits(v.y) << 16);
        o.y = (unsigned int)f2bfbits(v.z) | ((unsigned int)f2bfbits(v.w) << 16);
        ((uint2*)xb)[i] = o;
    } else {
        ((uint2*)xb)[i] = ((const uint2*)x)[i];
    }
}

// ---------------- batched CSR build for all 3 graphs ----------------
__global__ __launch_bounds__(256) void zero3(int* __restrict__ c) {
    int i = blockIdx.x * 256 + threadIdx.x;
    if (i < NC3) c[i] = 0;
}

__global__ __launch_bounds__(256) void count3(
    const int* __restrict__ e0, const int* __restrict__ e1, const int* __restrict__ e2,
    int* __restrict__ rp3, const int* __restrict__ flags)
{
    int i = blockIdx.x * 256 + threadIdx.x;          // [0, 3*N_EDGES)
    int g = i / N_EDGES;
    int il = i - g * N_EDGES;
    const int* e = (g == 0) ? e0 : (g == 1) ? e1 : e2;
    int dst = flags[1] ? e[2 * (N_EDGES + il)] : e[N_EDGES + il];
    atomicAdd(&rp3[g * N_NODES + dst], 1);
}

// local exclusive scan per 256-tile over concatenated counters, totals -> part[]
__global__ __launch_bounds__(256) void scan_k1(
    int* __restrict__ rp3, int* __restrict__ part)
{
    __shared__ int sa[256], sb[256];
    const int b = blockIdx.x, t = threadIdx.x, idx = b * 256 + t;
    int v = (idx < NC3) ? rp3[idx] : 0;
    sa[t] = v;
    __syncthreads();
    bool par = true;
#pragma unroll
    for (int off = 1; off < 256; off <<= 1) {
        if (par) { int x = sa[t] + (t >= off ? sa[t - off] : 0); sb[t] = x; }
        else     { int x = sb[t] + (t >= off ? sb[t - off] : 0); sa[t] = x; }
        par = !par;
        __syncthreads();
    }
    if (idx < NC3) rp3[idx] = sa[t] - v;             // local exclusive
    if (t == 255) part[b] = sa[255];
}

// exclusive-scan NB3 tile totals (1 block, looped)
__global__ __launch_bounds__(256) void scan_k2(int* __restrict__ part) {
    __shared__ int sa[256], sb[256];
    const int t = threadIdx.x;
    int run = 0;
    for (int j = 0; j < NB3; j += 256) {
        const int idx = j + t;
        int v = (idx < NB3) ? part[idx] : 0;
        sa[t] = v;
        __syncthreads();
        bool par = true;
#pragma unroll
        for (int off = 1; off < 256; off <<= 1) {
            if (par) { int x = sa[t] + (t >= off ? sa[t - off] : 0); sb[t] = x; }
            else     { int x = sb[t] + (t >= off ? sb[t - off] : 0); sa[t] = x; }
            par = !par;
            __syncthreads();
        }
        if (idx < NB3) part[idx] = run + sa[t] - v;  // exclusive
        run += sa[255];
        __syncthreads();
    }
}

// finalize rowptr (globally offset across graphs), init cursors, sentinel
__global__ __launch_bounds__(256) void scan_k3(
    int* __restrict__ rp3, const int* __restrict__ part, int* __restrict__ cur3)
{
    const int b = blockIdx.x, idx = b * 256 + threadIdx.x;
    if (idx < NC3) {
        int v = rp3[idx] + part[b];
        rp3[idx] = v;
        cur3[idx] = v;
    } else if (idx == NC3) {
        rp3[idx] = 3 * N_EDGES;                      // global sentinel
    }
}

// per-graph fill into the shared csr buffer (positions are global; re-base)
__global__ __launch_bounds__(256) void fill1(
    const int* __restrict__ e, int* __restrict__ cur_g, int* __restrict__ csr,
    int rbase, const int* __restrict__ flags)
{
    int i = blockIdx.x * 256 + threadIdx.x;
    int f = flags[1];
    int src = f ? e[2 * i] : e[i];
    int dst = f ? e[2 * (N_EDGES + i)] : e[N_EDGES + i];
    csr[atomicAdd(&cur_g[dst], 1) - rbase] = src;
}

// ---------------- fused layer (L0/L1) — gather/GEMM identical to r5/r6 (control) ----------------
template<int K>
__global__ __launch_bounds__(256) void sage_fused(
    const unsigned short* __restrict__ hin,   // [N,K] bf16
    const int* __restrict__ rp_g,             // per-graph rowptr (globally-offset values)
    const int* __restrict__ csr_src,          // shared csr buffer
    int rbase,                                // graph base in global positions
    const unsigned short* __restrict__ WlT,   // [256,K]
    const unsigned short* __restrict__ WrT,   // [256,K]
    const unsigned short* __restrict__ bb,    // [256]
    unsigned short* __restrict__ hout)        // [N,256]
{
    constexpr int CH = K / 8;
    constexpr int CAP = 3072;
    __shared__ unsigned short A0s[16][K + 8];
    __shared__ int sidx[CAP];
    __shared__ int srp[17];
    csr_src -= rbase;                          // re-base: global positions index local buffer
    const int tid = threadIdx.x;
    const int m0 = blockIdx.x * 16;
    if (tid < 17) srp[tid] = rp_g[m0 + tid];
    __syncthreads();
    const int base = srp[0];
    const int total = srp[16] - base;
    const bool staged = total <= CAP;
    if (staged) {
        for (int i = tid; i < total; i += 256) sidx[i] = csr_src[base + i];
    }
    __syncthreads();

    // ---- phase 1: gather + mean (r5-verified) ----
    for (int it = tid; it < 16 * CH; it += 256) {
        const int rr = it / CH;
        const int cc = it & (CH - 1);
        const int beg = srp[rr];
        const int deg = srp[rr + 1] - beg;
        const int begl = beg - base;
        float a[8], g[8];
#pragma unroll
        for (int v = 0; v < 8; ++v) { a[v] = 0.f; g[v] = 0.f; }
        const unsigned short* col = hin + cc * 8;
        auto run = [&](auto IDX) {
            int j = 0;
            for (; j + 3 < deg; j += 4) {
                int s0 = IDX(j), s1 = IDX(j + 1), s2 = IDX(j + 2), s3 = IDX(j + 3);
                uint4 v0 = *(const uint4*)(col + (size_t)s0 * K);
                uint4 v1 = *(const uint4*)(col + (size_t)s1 * K);
                uint4 v2 = *(const uint4*)(col + (size_t)s2 * K);
                uint4 v3 = *(const uint4*)(col + (size_t)s3 * K);
                acc8(a, v0); acc8(g, v1); acc8(a, v2); acc8(g, v3);
            }
            for (; j < deg; ++j) {
                uint4 v0 = *(const uint4*)(col + (size_t)IDX(j) * K);
                acc8(a, v0);
            }
        };
        if (staged) run([&](int j) { return sidx[begl + j]; });
        else        run([&](int j) { return csr_src[beg + j]; });
        const float inv = 1.0f / fmaxf((float)deg, 1.0f);
        short8 t8;
#pragma unroll
        for (int v = 0; v < 8; ++v) t8[v] = (short)f2bfbits((a[v] + g[v]) * inv);
        *(short8*)&A0s[rr][cc * 8] = t8;
    }
    __syncthreads();

    // ---- phase 2: MFMA dual GEMM + bias + relu (r4-verified) ----
    const int lane = tid & 63;
    const int wave = tid >> 6;
    const int r = lane & 15;
    const int quad = lane >> 4;
    short8 a0f[K / 32], a1f[K / 32];
#pragma unroll
    for (int k0 = 0; k0 < K / 32; ++k0)
        a0f[k0] = *(const short8*)&A0s[r][k0 * 32 + quad * 8];
    const unsigned short* hb = hin + (size_t)(m0 + r) * K + quad * 8;
#pragma unroll
    for (int k0 = 0; k0 < K / 32; ++k0)
        a1f[k0] = *(const short8*)(hb + k0 * 32);

    for (int nt = wave; nt < 16; nt += 4) {
        const int n0 = nt * 16;
        floatx4 acc = {0.f, 0.f, 0.f, 0.f};
        const unsigned short* b0 = WlT + (size_t)(n0 + r) * K + quad * 8;
        const unsigned short* b1 = WrT + (size_t)(n0 + r) * K + quad * 8;
#pragma unroll
        for (int k0 = 0; k0 < K / 32; ++k0)
            acc = __builtin_amdgcn_mfma_f32_16x16x32_bf16(a0f[k0], *(const short8*)(b0 + k0 * 32), acc, 0, 0, 0);
#pragma unroll
        for (int k0 = 0; k0 < K / 32; ++k0)
            acc = __builtin_amdgcn_mfma_f32_16x16x32_bf16(a1f[k0], *(const short8*)(b1 + k0 * 32), acc, 0, 0, 0);

        // C/D layout: col = lane&15, row = quad*4 + reg  [HW-verified]
        const int ccol = n0 + r;
        float bv = bfbits2f(bb[ccol]);
#pragma unroll
        for (int i = 0; i < 4; ++i) {
            float v = acc[i] + bv;
            v = v > 0.f ? v : 0.f;
            hout[(size_t)(m0 + quad * 4 + i) * 256 + ccol] = f2bfbits(v);
        }
    }
}

// ---------------- L2 GEMM pair (r5-verified) ----------------
__global__ __launch_bounds__(256) void gemm_pair(
    const unsigned short* __restrict__ A,
    const unsigned short* __restrict__ WT,
    unsigned short* __restrict__ out0,
    unsigned short* __restrict__ out1)
{
    const int tid = threadIdx.x, lane = tid & 63, wave = tid >> 6;
    const int m0 = blockIdx.x * 16;
    const int r = lane & 15, quad = lane >> 4;
    short8 af[8];
    const unsigned short* ab = A + (size_t)(m0 + r) * 256 + quad * 8;
#pragma unroll
    for (int k0 = 0; k0 < 8; ++k0) af[k0] = *(const short8*)(ab + k0 * 32);

    for (int nt = wave; nt < 16; nt += 4) {
        const int n0 = nt * 16;
        floatx4 acc = {0.f, 0.f, 0.f, 0.f};
        const unsigned short* b0 = WT + (size_t)(n0 + r) * 256 + quad * 8;
#pragma unroll
        for (int k0 = 0; k0 < 8; ++k0)
            acc = __builtin_amdgcn_mfma_f32_16x16x32_bf16(af[k0], *(const short8*)(b0 + k0 * 32), acc, 0, 0, 0);
        const int ccol = n0 + r;
#pragma unroll
        for (int i = 0; i < 4; ++i) {
            const size_t row = m0 + quad * 4 + i;
            unsigned short v = f2bfbits(acc[i]);
            if (ccol < 128) out0[row * 128 + ccol] = v;
            else            out1[row * 128 + ccol - 128] = v;
        }
    }
}

// ---------------- L2 aggregate + epilogue (r5-verified) ----------------
__global__ __launch_bounds__(256) void agg2(
    const unsigned short* __restrict__ hl2,
    const unsigned short* __restrict__ hr2,
    const int* __restrict__ rp_g,
    const int* __restrict__ csr_src,
    int rbase,
    const unsigned short* __restrict__ bb,
    void* __restrict__ out,
    const int* __restrict__ flags)
{
    constexpr int K = 128, CAP = 3072;
    __shared__ int sidx[CAP];
    __shared__ int srp[17];
    csr_src -= rbase;
    const int tid = threadIdx.x;
    const int m0 = blockIdx.x * 16;
    if (tid < 17) srp[tid] = rp_g[m0 + tid];
    __syncthreads();
    const int base = srp[0];
    const int total = srp[16] - base;
    const bool staged = total <= CAP;
    if (staged) {
        for (int i = tid; i < total; i += 256) sidx[i] = csr_src[base + i];
    }
    __syncthreads();

    const int rr = tid >> 4;
    const int cc = tid & 15;
    const int beg = srp[rr];
    const int deg = srp[rr + 1] - beg;
    const int begl = beg - base;
    float a[8], g[8];
#pragma unroll
    for (int v = 0; v < 8; ++v) { a[v] = 0.f; g[v] = 0.f; }
    const unsigned short* col = hl2 + cc * 8;
    auto run = [&](auto IDX) {
        int j = 0;
        for (; j + 3 < deg; j += 4) {
            int s0 = IDX(j), s1 = IDX(j + 1), s2 = IDX(j + 2), s3 = IDX(j + 3);
            uint4 v0 = *(const uint4*)(col + (size_t)s0 * K);
            uint4 v1 = *(const uint4*)(col + (size_t)s1 * K);
            uint4 v2 = *(const uint4*)(col + (size_t)s2 * K);
            uint4 v3 = *(const uint4*)(col + (size_t)s3 * K);
            acc8(a, v0); acc8(g, v1); acc8(a, v2); acc8(g, v3);
        }
        for (; j < deg; ++j) {
            uint4 v0 = *(const uint4*)(col + (size_t)IDX(j) * K);
            acc8(a, v0);
        }
    };
    if (staged) run([&](int j) { return sidx[begl + j]; });
    else        run([&](int j) { return csr_src[beg + j]; });

    const float inv = 1.0f / fmaxf((float)deg, 1.0f);
    const size_t ro = (size_t)(m0 + rr) * K + cc * 8;
    uint4 hv = *(const uint4*)(hr2 + ro);
    uint4 bv = *(const uint4*)(bb + cc * 8);
    float h8[8], b8[8];
    h8[0] = bfbits2f(hv.x & 0xffffu); h8[1] = bfbits2f(hv.x >> 16);
    h8[2] = bfbits2f(hv.y & 0xffffu); h8[3] = bfbits2f(hv.y >> 16);
    h8[4] = bfbits2f(hv.z & 0xffffu); h8[5] = bfbits2f(hv.z >> 16);
    h8[6] = bfbits2f(hv.w & 0xffffu); h8[7] = bfbits2f(hv.w >> 16);
    b8[0] = bfbits2f(bv.x & 0xffffu); b8[1] = bfbits2f(bv.x >> 16);
    b8[2] = bfbits2f(bv.y & 0xffffu); b8[3] = bfbits2f(bv.y >> 16);
    b8[4] = bfbits2f(bv.z & 0xffffu); b8[5] = bfbits2f(bv.z >> 16);
    b8[6] = bfbits2f(bv.w & 0xffffu); b8[7] = bfbits2f(bv.w >> 16);
    float o8[8];
#pragma unroll
    for (int v = 0; v < 8; ++v) {
        float m = (a[v] + g[v]) * inv + b8[v] + h8[v];
        o8[v] = m > 0.f ? m : 0.f;
    }
    if (flags[0]) {
        float* op = (float*)out + ro;
        float4 o0 = { o8[0], o8[1], o8[2], o8[3] };
        float4 o1 = { o8[4], o8[5], o8[6], o8[7] };
        *(float4*)op = o0;
        *(float4*)(op + 4) = o1;
    } else {
        short8 t8;
#pragma unroll
        for (int v = 0; v < 8; ++v) t8[v] = (short)f2bfbits(o8[v]);
        *(short8*)((unsigned short*)out + ro) = t8;
    }
}

// ---------------- orchestration ----------------
extern "C" void kernel_launch(void* const* d_in, const int* in_sizes, int n_in,
                              void* d_out, int out_size, void* d_ws, size_t ws_size,
                              hipStream_t stream) {
    const void* x  = d_in[0];
    const int* e[3] = { (const int*)d_in[1], (const int*)d_in[2], (const int*)d_in[3] };

    char* ws = (char*)d_ws;
    int* flags = (int*)ws;                                    // @0
    unsigned short* wt = (unsigned short*)(ws + 1024);        // 525,568 B -> 526,592
    unsigned short* bb0 = wt + 262144;
    unsigned short* bb1 = wt + 262400;
    unsigned short* bb2 = wt + 262656;
    int* rp3  = (int*)(ws + 526592);                          // 150,001 ints -> 1,126,596
    int* cur3 = (int*)(ws + 1126596);                         // 150,000 ints -> 1,726,596
    int* part = (int*)(ws + 1726608);                         // 586 ints -> 1,728,952
    int* csr  = (int*)(ws + 1728960);                         // 3.2 MB -> 4,928,960
    unsigned short* hA = (unsigned short*)(ws + 4928960);     // 25.6 MB -> 30,528,960
    unsigned short* hB = (unsigned short*)(ws + 30528960);    // 25.6 MB -> 56,128,960 (56.1 MB <= r6-proven 58.1)
    // overlays (lifetime-disjoint):
    unsigned short* xb  = hB;                 // dies when L1 fused writes hB
    unsigned short* hl2 = hA;                 // hA dead after L1 fused reads it
    unsigned short* hr2 = hA + (size_t)N_NODES * 128;

    detect<<<1, 256, 0, stream>>>((const unsigned short*)x, e[0], flags);
    prep_all<<<1027, 256, 0, stream>>>(d_in[4], d_in[6], d_in[7], d_in[9],
                                       d_in[10], d_in[12], d_in[5], d_in[8], d_in[11],
                                       wt, flags);
    cvt_x<<<6250, 256, 0, stream>>>(x, xb, flags);

    const int EG = N_EDGES / 256;     // 3125
    const int MG = N_NODES / 16;      // 3125

    // ---- batched CSR count+scan for all 3 graphs (one pipeline) ----
    zero3<<<NB3, 256, 0, stream>>>(rp3);
    count3<<<3 * EG, 256, 0, stream>>>(e[0], e[1], e[2], rp3, flags);
    scan_k1<<<NB3, 256, 0, stream>>>(rp3, part);
    scan_k2<<<1, 256, 0, stream>>>(part);
    scan_k3<<<NB3, 256, 0, stream>>>(rp3, part, cur3);

    // ---- layer 0: xb[.,128] -> hA[.,256] ----
    fill1<<<EG, 256, 0, stream>>>(e[0], cur3, csr, 0, flags);
    sage_fused<128><<<MG, 256, 0, stream>>>(xb, rp3, csr, 0, wt, wt + 32768, bb0, hA);

    // ---- layer 1: hA[.,256] -> hB[.,256] (clobbers xb — xb dead) ----
    fill1<<<EG, 256, 0, stream>>>(e[1], cur3 + N_NODES, csr, N_EDGES, flags);
    sage_fused<256><<<MG, 256, 0, stream>>>(hA, rp3 + N_NODES, csr, N_EDGES,
                                            wt + 65536, wt + 131072, bb1, hB);

    // ---- layer 2 (reordered): hl2 = hB@Wl2, hr2 = hB@Wr2; out = relu(mean(hl2)+b2+hr2) ----
    fill1<<<EG, 256, 0, stream>>>(e[2], cur3 + 2 * N_NODES, csr, 2 * N_EDGES, flags);
    gemm_pair<<<MG, 256, 0, stream>>>(hB, wt + 196608, hl2, hr2);   // writes over dead hA
    agg2<<<MG, 256, 0, stream>>>(hl2, hr2, rp3 + 2 * N_NODES, csr, 2 * N_EDGES,
                                 bb2, d_out, flags);
}

// Round 8
// 695.823 us; speedup vs baseline: 1.0758x; 1.0225x over previous
//
#include <hip/hip_runtime.h>
#include <hip/hip_bf16.h>
#include <stdint.h>

#define N_NODES 50000
#define N_EDGES 800000
#define NC3 150000               // 3 graphs x 50k counters
#define NB3 586                  // ceil(150016/256) tiles covering NC3+sentinel

typedef __attribute__((ext_vector_type(8))) short short8;
typedef __attribute__((ext_vector_type(4))) float floatx4;

__device__ __forceinline__ float bfbits2f(unsigned int u16) {
    union { unsigned int i; float f; } c; c.i = u16 << 16; return c.f;
}
__device__ __forceinline__ unsigned short f2bfbits(float f) {
    union { float f; unsigned int i; } c; c.f = f;
    unsigned int r = c.i + 0x7fffu + ((c.i >> 16) & 1u);   // RNE
    return (unsigned short)(r >> 16);
}
__device__ __forceinline__ void acc8(float* a, uint4 v) {
    a[0] += bfbits2f(v.x & 0xffffu); a[1] += bfbits2f(v.x >> 16);
    a[2] += bfbits2f(v.y & 0xffffu); a[3] += bfbits2f(v.y >> 16);
    a[4] += bfbits2f(v.z & 0xffffu); a[5] += bfbits2f(v.z >> 16);
    a[6] += bfbits2f(v.w & 0xffffu); a[7] += bfbits2f(v.w >> 16);
}

// ---------------- dtype detection (1 block) — verified r2, DO NOT TOUCH ----------------
__global__ __launch_bounds__(256) void detect(
    const unsigned short* __restrict__ x16, const int* __restrict__ e,
    int* __restrict__ flags)
{
    __shared__ int s_cnt[2];
    const int t = threadIdx.x;
    if (t < 2) s_cnt[t] = 0;
    __syncthreads();
    unsigned short v = x16[2 * t];
    int ex = (v >> 7) & 0xff;
    if (v == 0 || (ex >= 96 && ex <= 150)) atomicAdd(&s_cnt[0], 1);
    if (e[2 * t + 1] != 0) atomicAdd(&s_cnt[1], 1);
    __syncthreads();
    if (t == 0) {
        flags[0] = (s_cnt[0] < 200) ? 1 : 0;
        flags[1] = (s_cnt[1] < 128) ? 1 : 0;
    }
}

// ---------------- merged weight/bias prep + x->bf16 (r4 prep + r5 cvt, fused) ----------------
__global__ __launch_bounds__(256) void prep_cvt(
    const void* __restrict__ Wl0, const void* __restrict__ Wr0,
    const void* __restrict__ Wl1, const void* __restrict__ Wr1,
    const void* __restrict__ Wl2, const void* __restrict__ Wr2,
    const void* __restrict__ b0, const void* __restrict__ b1, const void* __restrict__ b2,
    unsigned short* __restrict__ wt,
    const void* __restrict__ x, unsigned short* __restrict__ xb,
    const int* __restrict__ flags)
{
    const int bid = blockIdx.x, t = threadIdx.x;
    const int f = flags[0];
    if (bid >= 1027) {                       // x conversion: 6250 blocks, 4 elems/thread
        int i = (bid - 1027) * 256 + t;
        if (f) {
            float4 v = ((const float4*)x)[i];
            uint2 o;
            o.x = (unsigned int)f2bfbits(v.x) | ((unsigned int)f2bfbits(v.y) << 16);
            o.y = (unsigned int)f2bfbits(v.z) | ((unsigned int)f2bfbits(v.w) << 16);
            ((uint2*)xb)[i] = o;
        } else {
            ((uint2*)xb)[i] = ((const uint2*)x)[i];
        }
        return;
    }
    if (bid >= 1024) {                       // biases
        const void* bs = bid == 1024 ? b0 : (bid == 1025 ? b1 : b2);
        unsigned short* bd = wt + 262144 + (bid - 1024) * 256;
        int n = (bid == 1026) ? 128 : 256;
        if (t < n) bd[t] = f ? f2bfbits(((const float*)bs)[t]) : ((const unsigned short*)bs)[t];
        return;
    }
    const void* W; unsigned short* WT; int K, N, off;
    if (bid < 128)      { W = Wl0; WT = wt;          K = 128; N = 256; off = bid; }
    else if (bid < 256) { W = Wr0; WT = wt + 32768;  K = 128; N = 256; off = bid - 128; }
    else if (bid < 512) { W = Wl1; WT = wt + 65536;  K = 256; N = 256; off = bid - 256; }
    else if (bid < 768) { W = Wr1; WT = wt + 131072; K = 256; N = 256; off = bid - 512; }
    else if (bid < 896) { W = Wl2; WT = wt + 196608; K = 256; N = 128; off = bid - 768; }
    else                { W = Wr2; WT = wt + 229376; K = 256; N = 128; off = bid - 896; }
    int idx = off * 256 + t;
    int k = idx / N, n = idx - k * N;
    unsigned short v = f ? f2bfbits(((const float*)W)[idx]) : ((const unsigned short*)W)[idx];
    WT[n * K + k] = v;
}

// ---------------- batched CSR build for all 3 graphs (r7-verified) ----------------
__global__ __launch_bounds__(256) void count3(
    const int* __restrict__ e0, const int* __restrict__ e1, const int* __restrict__ e2,
    int* __restrict__ rp3, const int* __restrict__ flags)
{
    int i = blockIdx.x * 256 + threadIdx.x;          // [0, 3*N_EDGES)
    int g = i / N_EDGES;
    int il = i - g * N_EDGES;
    const int* e = (g == 0) ? e0 : (g == 1) ? e1 : e2;
    int dst = flags[1] ? e[2 * (N_EDGES + il)] : e[N_EDGES + il];
    atomicAdd(&rp3[g * N_NODES + dst], 1);
}

__global__ __launch_bounds__(256) void scan_k1(
    int* __restrict__ rp3, int* __restrict__ part)
{
    __shared__ int sa[256], sb[256];
    const int b = blockIdx.x, t = threadIdx.x, idx = b * 256 + t;
    int v = (idx < NC3) ? rp3[idx] : 0;
    sa[t] = v;
    __syncthreads();
    bool par = true;
#pragma unroll
    for (int off = 1; off < 256; off <<= 1) {
        if (par) { int x = sa[t] + (t >= off ? sa[t - off] : 0); sb[t] = x; }
        else     { int x = sb[t] + (t >= off ? sb[t - off] : 0); sa[t] = x; }
        par = !par;
        __syncthreads();
    }
    if (idx < NC3) rp3[idx] = sa[t] - v;             // local exclusive
    if (t == 255) part[b] = sa[255];
}

__global__ __launch_bounds__(256) void scan_k2(int* __restrict__ part) {
    __shared__ int sa[256], sb[256];
    const int t = threadIdx.x;
    int run = 0;
    for (int j = 0; j < NB3; j += 256) {
        const int idx = j + t;
        int v = (idx < NB3) ? part[idx] : 0;
        sa[t] = v;
        __syncthreads();
        bool par = true;
#pragma unroll
        for (int off = 1; off < 256; off <<= 1) {
            if (par) { int x = sa[t] + (t >= off ? sa[t - off] : 0); sb[t] = x; }
            else     { int x = sb[t] + (t >= off ? sb[t - off] : 0); sa[t] = x; }
            par = !par;
            __syncthreads();
        }
        if (idx < NB3) part[idx] = run + sa[t] - v;  // exclusive
        run += sa[255];
        __syncthreads();
    }
}

__global__ __launch_bounds__(256) void scan_k3(
    int* __restrict__ rp3, const int* __restrict__ part, int* __restrict__ cur3)
{
    const int b = blockIdx.x, idx = b * 256 + threadIdx.x;
    if (idx < NC3) {
        int v = rp3[idx] + part[b];
        rp3[idx] = v;
        cur3[idx] = v;
    } else if (idx == NC3) {
        rp3[idx] = 3 * N_EDGES;                      // global sentinel
    }
}

__global__ __launch_bounds__(256) void fill1(
    const int* __restrict__ e, int* __restrict__ cur_g, int* __restrict__ csr,
    int rbase, const int* __restrict__ flags)
{
    int i = blockIdx.x * 256 + threadIdx.x;
    int f = flags[1];
    int src = f ? e[2 * i] : e[i];
    int dst = f ? e[2 * (N_EDGES + i)] : e[N_EDGES + i];
    csr[atomicAdd(&cur_g[dst], 1) - rbase] = src;
}

// ---------------- fused layer (L0/L1) — r7 structure, gather unroll-8 ----------------
template<int K>
__global__ __launch_bounds__(256) void sage_fused(
    const unsigned short* __restrict__ hin,   // [N,K] bf16
    const int* __restrict__ rp_g,             // per-graph rowptr (globally-offset values)
    const int* __restrict__ csr_src,          // shared csr buffer
    int rbase,
    const unsigned short* __restrict__ WlT,   // [256,K]
    const unsigned short* __restrict__ WrT,   // [256,K]
    const unsigned short* __restrict__ bb,    // [256]
    unsigned short* __restrict__ hout)        // [N,256]
{
    constexpr int CH = K / 8;
    constexpr int CAP = 3072;
    __shared__ unsigned short A0s[16][K + 8];
    __shared__ int sidx[CAP];
    __shared__ int srp[17];
    csr_src -= rbase;
    const int tid = threadIdx.x;
    const int m0 = blockIdx.x * 16;
    if (tid < 17) srp[tid] = rp_g[m0 + tid];
    __syncthreads();
    const int base = srp[0];
    const int total = srp[16] - base;
    const bool staged = total <= CAP;
    if (staged) {
        for (int i = tid; i < total; i += 256) sidx[i] = csr_src[base + i];
    }
    __syncthreads();

    // ---- phase 1: gather + mean (unroll-8 — concurrency probe r8) ----
    for (int it = tid; it < 16 * CH; it += 256) {
        const int rr = it / CH;
        const int cc = it & (CH - 1);
        const int beg = srp[rr];
        const int deg = srp[rr + 1] - beg;
        const int begl = beg - base;
        float a[8], g[8];
#pragma unroll
        for (int v = 0; v < 8; ++v) { a[v] = 0.f; g[v] = 0.f; }
        const unsigned short* col = hin + cc * 8;
        auto run = [&](auto IDX) {
            int j = 0;
            for (; j + 7 < deg; j += 8) {
                int s0 = IDX(j),     s1 = IDX(j + 1), s2 = IDX(j + 2), s3 = IDX(j + 3);
                int s4 = IDX(j + 4), s5 = IDX(j + 5), s6 = IDX(j + 6), s7 = IDX(j + 7);
                uint4 v0 = *(const uint4*)(col + (size_t)s0 * K);
                uint4 v1 = *(const uint4*)(col + (size_t)s1 * K);
                uint4 v2 = *(const uint4*)(col + (size_t)s2 * K);
                uint4 v3 = *(const uint4*)(col + (size_t)s3 * K);
                uint4 v4 = *(const uint4*)(col + (size_t)s4 * K);
                uint4 v5 = *(const uint4*)(col + (size_t)s5 * K);
                uint4 v6 = *(const uint4*)(col + (size_t)s6 * K);
                uint4 v7 = *(const uint4*)(col + (size_t)s7 * K);
                acc8(a, v0); acc8(g, v1); acc8(a, v2); acc8(g, v3);
                acc8(a, v4); acc8(g, v5); acc8(a, v6); acc8(g, v7);
            }
            for (; j + 1 < deg; j += 2) {
                int s0 = IDX(j), s1 = IDX(j + 1);
                uint4 v0 = *(const uint4*)(col + (size_t)s0 * K);
                uint4 v1 = *(const uint4*)(col + (size_t)s1 * K);
                acc8(a, v0); acc8(g, v1);
            }
            if (j < deg) {
                uint4 v0 = *(const uint4*)(col + (size_t)IDX(j) * K);
                acc8(a, v0);
            }
        };
        if (staged) run([&](int j) { return sidx[begl + j]; });
        else        run([&](int j) { return csr_src[beg + j]; });
        const float inv = 1.0f / fmaxf((float)deg, 1.0f);
        short8 t8;
#pragma unroll
        for (int v = 0; v < 8; ++v) t8[v] = (short)f2bfbits((a[v] + g[v]) * inv);
        *(short8*)&A0s[rr][cc * 8] = t8;
    }
    __syncthreads();

    // ---- phase 2: MFMA dual GEMM + bias + relu (r4-verified) ----
    const int lane = tid & 63;
    const int wave = tid >> 6;
    const int r = lane & 15;
    const int quad = lane >> 4;
    short8 a0f[K / 32], a1f[K / 32];
#pragma unroll
    for (int k0 = 0; k0 < K / 32; ++k0)
        a0f[k0] = *(const short8*)&A0s[r][k0 * 32 + quad * 8];
    const unsigned short* hb = hin + (size_t)(m0 + r) * K + quad * 8;
#pragma unroll
    for (int k0 = 0; k0 < K / 32; ++k0)
        a1f[k0] = *(const short8*)(hb + k0 * 32);

    for (int nt = wave; nt < 16; nt += 4) {
        const int n0 = nt * 16;
        floatx4 acc = {0.f, 0.f, 0.f, 0.f};
        const unsigned short* b0 = WlT + (size_t)(n0 + r) * K + quad * 8;
        const unsigned short* b1 = WrT + (size_t)(n0 + r) * K + quad * 8;
#pragma unroll
        for (int k0 = 0; k0 < K / 32; ++k0)
            acc = __builtin_amdgcn_mfma_f32_16x16x32_bf16(a0f[k0], *(const short8*)(b0 + k0 * 32), acc, 0, 0, 0);
#pragma unroll
        for (int k0 = 0; k0 < K / 32; ++k0)
            acc = __builtin_amdgcn_mfma_f32_16x16x32_bf16(a1f[k0], *(const short8*)(b1 + k0 * 32), acc, 0, 0, 0);

        // C/D layout: col = lane&15, row = quad*4 + reg  [HW-verified]
        const int ccol = n0 + r;
        float bv = bfbits2f(bb[ccol]);
#pragma unroll
        for (int i = 0; i < 4; ++i) {
            float v = acc[i] + bv;
            v = v > 0.f ? v : 0.f;
            hout[(size_t)(m0 + quad * 4 + i) * 256 + ccol] = f2bfbits(v);
        }
    }
}

// ---------------- L2 GEMM pair (r5-verified) ----------------
__global__ __launch_bounds__(256) void gemm_pair(
    const unsigned short* __restrict__ A,
    const unsigned short* __restrict__ WT,
    unsigned short* __restrict__ out0,
    unsigned short* __restrict__ out1)
{
    const int tid = threadIdx.x, lane = tid & 63, wave = tid >> 6;
    const int m0 = blockIdx.x * 16;
    const int r = lane & 15, quad = lane >> 4;
    short8 af[8];
    const unsigned short* ab = A + (size_t)(m0 + r) * 256 + quad * 8;
#pragma unroll
    for (int k0 = 0; k0 < 8; ++k0) af[k0] = *(const short8*)(ab + k0 * 32);

    for (int nt = wave; nt < 16; nt += 4) {
        const int n0 = nt * 16;
        floatx4 acc = {0.f, 0.f, 0.f, 0.f};
        const unsigned short* b0 = WT + (size_t)(n0 + r) * 256 + quad * 8;
#pragma unroll
        for (int k0 = 0; k0 < 8; ++k0)
            acc = __builtin_amdgcn_mfma_f32_16x16x32_bf16(af[k0], *(const short8*)(b0 + k0 * 32), acc, 0, 0, 0);
        const int ccol = n0 + r;
#pragma unroll
        for (int i = 0; i < 4; ++i) {
            const size_t row = m0 + quad * 4 + i;
            unsigned short v = f2bfbits(acc[i]);
            if (ccol < 128) out0[row * 128 + ccol] = v;
            else            out1[row * 128 + ccol - 128] = v;
        }
    }
}

// ---------------- L2 aggregate + epilogue (r5-verified; gather unroll-8) ----------------
__global__ __launch_bounds__(256) void agg2(
    const unsigned short* __restrict__ hl2,
    const unsigned short* __restrict__ hr2,
    const int* __restrict__ rp_g,
    const int* __restrict__ csr_src,
    int rbase,
    const unsigned short* __restrict__ bb,
    void* __restrict__ out,
    const int* __restrict__ flags)
{
    constexpr int K = 128, CAP = 3072;
    __shared__ int sidx[CAP];
    __shared__ int srp[17];
    csr_src -= rbase;
    const int tid = threadIdx.x;
    const int m0 = blockIdx.x * 16;
    if (tid < 17) srp[tid] = rp_g[m0 + tid];
    __syncthreads();
    const int base = srp[0];
    const int total = srp[16] - base;
    const bool staged = total <= CAP;
    if (staged) {
        for (int i = tid; i < total; i += 256) sidx[i] = csr_src[base + i];
    }
    __syncthreads();

    const int rr = tid >> 4;
    const int cc = tid & 15;
    const int beg = srp[rr];
    const int deg = srp[rr + 1] - beg;
    const int begl = beg - base;
    float a[8], g[8];
#pragma unroll
    for (int v = 0; v < 8; ++v) { a[v] = 0.f; g[v] = 0.f; }
    const unsigned short* col = hl2 + cc * 8;
    auto run = [&](auto IDX) {
        int j = 0;
        for (; j + 7 < deg; j += 8) {
            int s0 = IDX(j),     s1 = IDX(j + 1), s2 = IDX(j + 2), s3 = IDX(j + 3);
            int s4 = IDX(j + 4), s5 = IDX(j + 5), s6 = IDX(j + 6), s7 = IDX(j + 7);
            uint4 v0 = *(const uint4*)(col + (size_t)s0 * K);
            uint4 v1 = *(const uint4*)(col + (size_t)s1 * K);
            uint4 v2 = *(const uint4*)(col + (size_t)s2 * K);
            uint4 v3 = *(const uint4*)(col + (size_t)s3 * K);
            uint4 v4 = *(const uint4*)(col + (size_t)s4 * K);
            uint4 v5 = *(const uint4*)(col + (size_t)s5 * K);
            uint4 v6 = *(const uint4*)(col + (size_t)s6 * K);
            uint4 v7 = *(const uint4*)(col + (size_t)s7 * K);
            acc8(a, v0); acc8(g, v1); acc8(a, v2); acc8(g, v3);
            acc8(a, v4); acc8(g, v5); acc8(a, v6); acc8(g, v7);
        }
        for (; j + 1 < deg; j += 2) {
            int s0 = IDX(j), s1 = IDX(j + 1);
            uint4 v0 = *(const uint4*)(col + (size_t)s0 * K);
            uint4 v1 = *(const uint4*)(col + (size_t)s1 * K);
            acc8(a, v0); acc8(g, v1);
        }
        if (j < deg) {
            uint4 v0 = *(const uint4*)(col + (size_t)IDX(j) * K);
            acc8(a, v0);
        }
    };
    if (staged) run([&](int j) { return sidx[begl + j]; });
    else        run([&](int j) { return csr_src[beg + j]; });

    const float inv = 1.0f / fmaxf((float)deg, 1.0f);
    const size_t ro = (size_t)(m0 + rr) * K + cc * 8;
    uint4 hv = *(const uint4*)(hr2 + ro);
    uint4 bv = *(const uint4*)(bb + cc * 8);
    float h8[8], b8[8];
    h8[0] = bfbits2f(hv.x & 0xffffu); h8[1] = bfbits2f(hv.x >> 16);
    h8[2] = bfbits2f(hv.y & 0xffffu); h8[3] = bfbits2f(hv.y >> 16);
    h8[4] = bfbits2f(hv.z & 0xffffu); h8[5] = bfbits2f(hv.z >> 16);
    h8[6] = bfbits2f(hv.w & 0xffffu); h8[7] = bfbits2f(hv.w >> 16);
    b8[0] = bfbits2f(bv.x & 0xffffu); b8[1] = bfbits2f(bv.x >> 16);
    b8[2] = bfbits2f(bv.y & 0xffffu); b8[3] = bfbits2f(bv.y >> 16);
    b8[4] = bfbits2f(bv.z & 0xffffu); b8[5] = bfbits2f(bv.z >> 16);
    b8[6] = bfbits2f(bv.w & 0xffffu); b8[7] = bfbits2f(bv.w >> 16);
    float o8[8];
#pragma unroll
    for (int v = 0; v < 8; ++v) {
        float m = (a[v] + g[v]) * inv + b8[v] + h8[v];
        o8[v] = m > 0.f ? m : 0.f;
    }
    if (flags[0]) {
        float* op = (float*)out + ro;
        float4 o0 = { o8[0], o8[1], o8[2], o8[3] };
        float4 o1 = { o8[4], o8[5], o8[6], o8[7] };
        *(float4*)op = o0;
        *(float4*)(op + 4) = o1;
    } else {
        short8 t8;
#pragma unroll
        for (int v = 0; v < 8; ++v) t8[v] = (short)f2bfbits(o8[v]);
        *(short8*)((unsigned short*)out + ro) = t8;
    }
}

// ---------------- orchestration ----------------
extern "C" void kernel_launch(void* const* d_in, const int* in_sizes, int n_in,
                              void* d_out, int out_size, void* d_ws, size_t ws_size,
                              hipStream_t stream) {
    const void* x  = d_in[0];
    const int* e[3] = { (const int*)d_in[1], (const int*)d_in[2], (const int*)d_in[3] };

    char* ws = (char*)d_ws;
    int* flags = (int*)ws;                                    // @0
    unsigned short* wt = (unsigned short*)(ws + 1024);        // 525,568 B -> 526,592
    unsigned short* bb0 = wt + 262144;
    unsigned short* bb1 = wt + 262400;
    unsigned short* bb2 = wt + 262656;
    int* rp3  = (int*)(ws + 526592);                          // 150,001 ints -> 1,126,596
    int* cur3 = (int*)(ws + 1126596);                         // 150,000 ints -> 1,726,596
    int* part = (int*)(ws + 1726608);                         // 586 ints -> 1,728,952
    int* csr  = (int*)(ws + 1728960);                         // 3.2 MB -> 4,928,960
    unsigned short* hA = (unsigned short*)(ws + 4928960);     // 25.6 MB -> 30,528,960
    unsigned short* hB = (unsigned short*)(ws + 30528960);    // 25.6 MB -> 56,128,960 (56.1 MB, r7-proven)
    unsigned short* xb  = hB;                 // overlay: dies when L1 fused writes hB
    unsigned short* hl2 = hA;                 // overlay: hA dead after L1 fused reads it
    unsigned short* hr2 = hA + (size_t)N_NODES * 128;

    detect<<<1, 256, 0, stream>>>((const unsigned short*)x, e[0], flags);
    prep_cvt<<<7277, 256, 0, stream>>>(d_in[4], d_in[6], d_in[7], d_in[9],
                                       d_in[10], d_in[12], d_in[5], d_in[8], d_in[11],
                                       wt, x, xb, flags);

    const int EG = N_EDGES / 256;     // 3125
    const int MG = N_NODES / 16;      // 3125

    // ---- batched CSR count+scan for all 3 graphs ----
    hipMemsetAsync(rp3, 0, (size_t)NC3 * sizeof(int), stream);
    count3<<<3 * EG, 256, 0, stream>>>(e[0], e[1], e[2], rp3, flags);
    scan_k1<<<NB3, 256, 0, stream>>>(rp3, part);
    scan_k2<<<1, 256, 0, stream>>>(part);
    scan_k3<<<NB3, 256, 0, stream>>>(rp3, part, cur3);

    // ---- layer 0: xb[.,128] -> hA[.,256] ----
    fill1<<<EG, 256, 0, stream>>>(e[0], cur3, csr, 0, flags);
    sage_fused<128><<<MG, 256, 0, stream>>>(xb, rp3, csr, 0, wt, wt + 32768, bb0, hA);

    // ---- layer 1: hA[.,256] -> hB[.,256] (clobbers xb — xb dead) ----
    fill1<<<EG, 256, 0, stream>>>(e[1], cur3 + N_NODES, csr, N_EDGES, flags);
    sage_fused<256><<<MG, 256, 0, stream>>>(hA, rp3 + N_NODES, csr, N_EDGES,
                                            wt + 65536, wt + 131072, bb1, hB);

    // ---- layer 2 (reordered): hl2 = hB@Wl2, hr2 = hB@Wr2; out = relu(mean(hl2)+b2+hr2) ----
    fill1<<<EG, 256, 0, stream>>>(e[2], cur3 + 2 * N_NODES, csr, 2 * N_EDGES, flags);
    gemm_pair<<<MG, 256, 0, stream>>>(hB, wt + 196608, hl2, hr2);   // writes over dead hA
    agg2<<<MG, 256, 0, stream>>>(hl2, hr2, rp3 + 2 * N_NODES, csr, 2 * N_EDGES,
                                 bb2, d_out, flags);
}

// Round 9
// 690.505 us; speedup vs baseline: 1.0841x; 1.0077x over previous
//
#include <hip/hip_runtime.h>
#include <hip/hip_bf16.h>
#include <stdint.h>

#define N_NODES 50000
#define N_EDGES 800000
#define NC3 150000               // 3 graphs x 50k counters
#define NB3 586                  // ceil(150000/256)
#define MG 3125                  // N_NODES/16 m-tiles
#define EG 3125                  // N_EDGES/256 edge blocks

typedef __attribute__((ext_vector_type(8))) short short8;
typedef __attribute__((ext_vector_type(4))) float floatx4;

__device__ __forceinline__ float bfbits2f(unsigned int u16) {
    union { unsigned int i; float f; } c; c.i = u16 << 16; return c.f;
}
__device__ __forceinline__ unsigned short f2bfbits(float f) {
    union { float f; unsigned int i; } c; c.f = f;
    unsigned int r = c.i + 0x7fffu + ((c.i >> 16) & 1u);   // RNE
    return (unsigned short)(r >> 16);
}
__device__ __forceinline__ void acc8(float* a, uint4 v) {
    a[0] += bfbits2f(v.x & 0xffffu); a[1] += bfbits2f(v.x >> 16);
    a[2] += bfbits2f(v.y & 0xffffu); a[3] += bfbits2f(v.y >> 16);
    a[4] += bfbits2f(v.z & 0xffffu); a[5] += bfbits2f(v.z >> 16);
    a[6] += bfbits2f(v.w & 0xffffu); a[7] += bfbits2f(v.w >> 16);
}

// ---- mega1: per-block local dtype detect + weight/bias prep + x->bf16 + count3 ----
// grid = 16653: [0,1027) weights/biases, [1027,7277) cvt_x, [7277,16652) count3,
// 16652 = store flags for later dispatches. detect logic verified r2.
__global__ __launch_bounds__(256) void mega1(
    const void* __restrict__ Wl0, const void* __restrict__ Wr0,
    const void* __restrict__ Wl1, const void* __restrict__ Wr1,
    const void* __restrict__ Wl2, const void* __restrict__ Wr2,
    const void* __restrict__ b0, const void* __restrict__ b1, const void* __restrict__ b2,
    unsigned short* __restrict__ wt,
    const void* __restrict__ x, unsigned short* __restrict__ xb,
    const int* __restrict__ e0, const int* __restrict__ e1, const int* __restrict__ e2,
    int* __restrict__ rp3, int* __restrict__ flagsOut)
{
    __shared__ int s_cnt[2];
    const int t = threadIdx.x;
    if (t < 2) s_cnt[t] = 0;
    __syncthreads();
    {   // local detect (r2-verified logic)
        unsigned short v = ((const unsigned short*)x)[2 * t];
        int ex = (v >> 7) & 0xff;
        if (v == 0 || (ex >= 96 && ex <= 150)) atomicAdd(&s_cnt[0], 1);
        if (e0[2 * t + 1] != 0) atomicAdd(&s_cnt[1], 1);
    }
    __syncthreads();
    const int f0 = (s_cnt[0] < 200) ? 1 : 0;
    const int f1 = (s_cnt[1] < 128) ? 1 : 0;
    const int bid = blockIdx.x;

    if (bid == 16652) {
        if (t == 0) { flagsOut[0] = f0; flagsOut[1] = f1; }
        return;
    }
    if (bid >= 7277) {                       // count3
        int i = (bid - 7277) * 256 + t;      // [0, 3*N_EDGES)
        int g = i / N_EDGES;
        int il = i - g * N_EDGES;
        const int* e = (g == 0) ? e0 : (g == 1) ? e1 : e2;
        int dst = f1 ? e[2 * (N_EDGES + il)] : e[N_EDGES + il];
        atomicAdd(&rp3[g * N_NODES + dst], 1);
        return;
    }
    if (bid >= 1027) {                       // cvt_x: 6250 blocks, 4 elems/thread
        int i = (bid - 1027) * 256 + t;
        if (f0) {
            float4 v = ((const float4*)x)[i];
            uint2 o;
            o.x = (unsigned int)f2bfbits(v.x) | ((unsigned int)f2bfbits(v.y) << 16);
            o.y = (unsigned int)f2bfbits(v.z) | ((unsigned int)f2bfbits(v.w) << 16);
            ((uint2*)xb)[i] = o;
        } else {
            ((uint2*)xb)[i] = ((const uint2*)x)[i];
        }
        return;
    }
    if (bid >= 1024) {                       // biases
        const void* bs = bid == 1024 ? b0 : (bid == 1025 ? b1 : b2);
        unsigned short* bd = wt + 262144 + (bid - 1024) * 256;
        int n = (bid == 1026) ? 128 : 256;
        if (t < n) bd[t] = f0 ? f2bfbits(((const float*)bs)[t]) : ((const unsigned short*)bs)[t];
        return;
    }
    const void* W; unsigned short* WT; int K, N, off;
    if (bid < 128)      { W = Wl0; WT = wt;          K = 128; N = 256; off = bid; }
    else if (bid < 256) { W = Wr0; WT = wt + 32768;  K = 128; N = 256; off = bid - 128; }
    else if (bid < 512) { W = Wl1; WT = wt + 65536;  K = 256; N = 256; off = bid - 256; }
    else if (bid < 768) { W = Wr1; WT = wt + 131072; K = 256; N = 256; off = bid - 512; }
    else if (bid < 896) { W = Wl2; WT = wt + 196608; K = 256; N = 128; off = bid - 768; }
    else                { W = Wr2; WT = wt + 229376; K = 256; N = 128; off = bid - 896; }
    int idx = off * 256 + t;
    int k = idx / N, n = idx - k * N;
    unsigned short v = f0 ? f2bfbits(((const float*)W)[idx]) : ((const unsigned short*)W)[idx];
    WT[n * K + k] = v;
}

// ---- scan12: per-tile local exclusive scan; last block scans the 586 partials ----
__global__ __launch_bounds__(256) void scan12(
    int* __restrict__ rp3, int* __restrict__ part, int* __restrict__ ticket)
{
    __shared__ int sa[256], sb[256];
    __shared__ int lastBlk;
    const int b = blockIdx.x, t = threadIdx.x, idx = b * 256 + t;
    int v = (idx < NC3) ? rp3[idx] : 0;
    sa[t] = v;
    __syncthreads();
    bool par = true;
#pragma unroll
    for (int off = 1; off < 256; off <<= 1) {
        if (par) { int x = sa[t] + (t >= off ? sa[t - off] : 0); sb[t] = x; }
        else     { int x = sb[t] + (t >= off ? sb[t - off] : 0); sa[t] = x; }
        par = !par;
        __syncthreads();
    }
    if (idx < NC3) rp3[idx] = sa[t] - v;             // local exclusive
    if (t == 255) part[b] = sa[255];
    __threadfence();                                  // publish before ticket
    if (t == 0) lastBlk = (atomicAdd(ticket, 1) == gridDim.x - 1) ? 1 : 0;
    __syncthreads();
    if (!lastBlk) return;

    // global exclusive scan of part[0..NB3)
    int run = 0;
    for (int j = 0; j < NB3; j += 256) {
        const int i2 = j + t;
        int pv = (i2 < NB3) ? atomicAdd(&part[i2], 0) : 0;   // coherent read
        sa[t] = pv;
        __syncthreads();
        bool p2 = true;
#pragma unroll
        for (int off = 1; off < 256; off <<= 1) {
            if (p2) { int x = sa[t] + (t >= off ? sa[t - off] : 0); sb[t] = x; }
            else    { int x = sb[t] + (t >= off ? sb[t - off] : 0); sa[t] = x; }
            p2 = !p2;
            __syncthreads();
        }
        if (i2 < NB3) part[i2] = run + sa[t] - pv;   // global exclusive
        run += sa[255];
        __syncthreads();
    }
}

// ---- fill: uses rp3 itself as cursor (consumers read boundaries at idx-1) ----
__device__ __forceinline__ void fill_body(
    int i, const int* __restrict__ e, int* __restrict__ rp3,
    const int* __restrict__ part, int* __restrict__ csr, int g, int f1)
{
    int src = f1 ? e[2 * i] : e[i];
    int dst = f1 ? e[2 * (N_EDGES + i)] : e[N_EDGES + i];
    int gidx = g * N_NODES + dst;
    int pos = part[gidx >> 8] + atomicAdd(&rp3[gidx], 1);
    csr[pos - g * N_EDGES] = src;
}

__global__ __launch_bounds__(256) void fill_k(
    const int* __restrict__ e, int* __restrict__ rp3, const int* __restrict__ part,
    int* __restrict__ csr, int g, const int* __restrict__ flags)
{
    fill_body(blockIdx.x * 256 + threadIdx.x, e, rp3, part, csr, g, flags[1]);
}

// ---- fused layer (L0/L1): gather unroll-8 + MFMA dual GEMM (r8 control body) ----
template<int K>
__global__ __launch_bounds__(256) void sage_fused(
    const unsigned short* __restrict__ hin,   // [N,K] bf16
    const int* __restrict__ rp3,              // full concatenated (post-fill) rowptr
    const int* __restrict__ part,             // tile offsets
    const int* __restrict__ csr_src,          // this graph's csr buffer
    int gbase, int rbase,                     // g*N_NODES, g*N_EDGES
    const unsigned short* __restrict__ WlT,
    const unsigned short* __restrict__ WrT,
    const unsigned short* __restrict__ bb,
    unsigned short* __restrict__ hout)        // [N,256]
{
    constexpr int CH = K / 8;
    constexpr int CAP = 3072;
    __shared__ unsigned short A0s[16][K + 8];
    __shared__ int sidx[CAP];
    __shared__ int srp[17];
    csr_src -= rbase;
    const int tid = threadIdx.x;
    const int m0 = blockIdx.x * 16;
    if (tid < 17) {
        int idx = gbase + m0 + tid - 1;       // boundary of node = prefix of idx+1
        srp[tid] = (idx < 0) ? 0 : rp3[idx] + part[idx >> 8];
    }
    __syncthreads();
    const int base = srp[0];
    const int total = srp[16] - base;
    const bool staged = total <= CAP;
    if (staged) {
        for (int i = tid; i < total; i += 256) sidx[i] = csr_src[base + i];
    }
    __syncthreads();

    // phase 1: gather + mean (unroll-8, r8-verified)
    for (int it = tid; it < 16 * CH; it += 256) {
        const int rr = it / CH;
        const int cc = it & (CH - 1);
        const int beg = srp[rr];
        const int deg = srp[rr + 1] - beg;
        const int begl = beg - base;
        float a[8], g[8];
#pragma unroll
        for (int v = 0; v < 8; ++v) { a[v] = 0.f; g[v] = 0.f; }
        const unsigned short* col = hin + cc * 8;
        auto run = [&](auto IDX) {
            int j = 0;
            for (; j + 7 < deg; j += 8) {
                int s0 = IDX(j),     s1 = IDX(j + 1), s2 = IDX(j + 2), s3 = IDX(j + 3);
                int s4 = IDX(j + 4), s5 = IDX(j + 5), s6 = IDX(j + 6), s7 = IDX(j + 7);
                uint4 v0 = *(const uint4*)(col + (size_t)s0 * K);
                uint4 v1 = *(const uint4*)(col + (size_t)s1 * K);
                uint4 v2 = *(const uint4*)(col + (size_t)s2 * K);
                uint4 v3 = *(const uint4*)(col + (size_t)s3 * K);
                uint4 v4 = *(const uint4*)(col + (size_t)s4 * K);
                uint4 v5 = *(const uint4*)(col + (size_t)s5 * K);
                uint4 v6 = *(const uint4*)(col + (size_t)s6 * K);
                uint4 v7 = *(const uint4*)(col + (size_t)s7 * K);
                acc8(a, v0); acc8(g, v1); acc8(a, v2); acc8(g, v3);
                acc8(a, v4); acc8(g, v5); acc8(a, v6); acc8(g, v7);
            }
            for (; j + 1 < deg; j += 2) {
                int s0 = IDX(j), s1 = IDX(j + 1);
                uint4 v0 = *(const uint4*)(col + (size_t)s0 * K);
                uint4 v1 = *(const uint4*)(col + (size_t)s1 * K);
                acc8(a, v0); acc8(g, v1);
            }
            if (j < deg) {
                uint4 v0 = *(const uint4*)(col + (size_t)IDX(j) * K);
                acc8(a, v0);
            }
        };
        if (staged) run([&](int j) { return sidx[begl + j]; });
        else        run([&](int j) { return csr_src[beg + j]; });
        const float inv = 1.0f / fmaxf((float)deg, 1.0f);
        short8 t8;
#pragma unroll
        for (int v = 0; v < 8; ++v) t8[v] = (short)f2bfbits((a[v] + g[v]) * inv);
        *(short8*)&A0s[rr][cc * 8] = t8;
    }
    __syncthreads();

    // phase 2: MFMA dual GEMM + bias + relu (r4-verified)
    const int lane = tid & 63;
    const int wave = tid >> 6;
    const int r = lane & 15;
    const int quad = lane >> 4;
    short8 a0f[K / 32], a1f[K / 32];
#pragma unroll
    for (int k0 = 0; k0 < K / 32; ++k0)
        a0f[k0] = *(const short8*)&A0s[r][k0 * 32 + quad * 8];
    const unsigned short* hb = hin + (size_t)(m0 + r) * K + quad * 8;
#pragma unroll
    for (int k0 = 0; k0 < K / 32; ++k0)
        a1f[k0] = *(const short8*)(hb + k0 * 32);

    for (int nt = wave; nt < 16; nt += 4) {
        const int n0 = nt * 16;
        floatx4 acc = {0.f, 0.f, 0.f, 0.f};
        const unsigned short* b0 = WlT + (size_t)(n0 + r) * K + quad * 8;
        const unsigned short* b1 = WrT + (size_t)(n0 + r) * K + quad * 8;
#pragma unroll
        for (int k0 = 0; k0 < K / 32; ++k0)
            acc = __builtin_amdgcn_mfma_f32_16x16x32_bf16(a0f[k0], *(const short8*)(b0 + k0 * 32), acc, 0, 0, 0);
#pragma unroll
        for (int k0 = 0; k0 < K / 32; ++k0)
            acc = __builtin_amdgcn_mfma_f32_16x16x32_bf16(a1f[k0], *(const short8*)(b1 + k0 * 32), acc, 0, 0, 0);

        // C/D layout: col = lane&15, row = quad*4 + reg  [HW-verified]
        const int ccol = n0 + r;
        float bv = bfbits2f(bb[ccol]);
#pragma unroll
        for (int i = 0; i < 4; ++i) {
            float v = acc[i] + bv;
            v = v > 0.f ? v : 0.f;
            hout[(size_t)(m0 + quad * 4 + i) * 256 + ccol] = f2bfbits(v);
        }
    }
}

// ---- L2 GEMM pair + fill(e2) merged: blocks [0,MG) gemm, [MG,2MG) fill ----
__global__ __launch_bounds__(256) void gemm_fill(
    const unsigned short* __restrict__ A,
    const unsigned short* __restrict__ WT,
    unsigned short* __restrict__ out0,
    unsigned short* __restrict__ out1,
    const int* __restrict__ e2, int* __restrict__ rp3, const int* __restrict__ part,
    int* __restrict__ csr, const int* __restrict__ flags)
{
    const int tid = threadIdx.x;
    if (blockIdx.x >= MG) {
        fill_body((blockIdx.x - MG) * 256 + tid, e2, rp3, part, csr, 2, flags[1]);
        return;
    }
    const int lane = tid & 63, wave = tid >> 6;
    const int m0 = blockIdx.x * 16;
    const int r = lane & 15, quad = lane >> 4;
    short8 af[8];
    const unsigned short* ab = A + (size_t)(m0 + r) * 256 + quad * 8;
#pragma unroll
    for (int k0 = 0; k0 < 8; ++k0) af[k0] = *(const short8*)(ab + k0 * 32);

    for (int nt = wave; nt < 16; nt += 4) {
        const int n0 = nt * 16;
        floatx4 acc = {0.f, 0.f, 0.f, 0.f};
        const unsigned short* b0 = WT + (size_t)(n0 + r) * 256 + quad * 8;
#pragma unroll
        for (int k0 = 0; k0 < 8; ++k0)
            acc = __builtin_amdgcn_mfma_f32_16x16x32_bf16(af[k0], *(const short8*)(b0 + k0 * 32), acc, 0, 0, 0);
        const int ccol = n0 + r;
#pragma unroll
        for (int i = 0; i < 4; ++i) {
            const size_t row = m0 + quad * 4 + i;
            unsigned short v = f2bfbits(acc[i]);
            if (ccol < 128) out0[row * 128 + ccol] = v;
            else            out1[row * 128 + ccol - 128] = v;
        }
    }
}

// ---- L2 aggregate + epilogue (r8 body; srp via rp3+part) ----
__global__ __launch_bounds__(256) void agg2(
    const unsigned short* __restrict__ hl2,
    const unsigned short* __restrict__ hr2,
    const int* __restrict__ rp3, const int* __restrict__ part,
    const int* __restrict__ csr_src,
    const unsigned short* __restrict__ bb,
    void* __restrict__ out,
    const int* __restrict__ flags)
{
    constexpr int K = 128, CAP = 3072;
    constexpr int gbase = 2 * N_NODES, rbase = 2 * N_EDGES;
    __shared__ int sidx[CAP];
    __shared__ int srp[17];
    csr_src -= rbase;
    const int tid = threadIdx.x;
    const int m0 = blockIdx.x * 16;
    if (tid < 17) {
        int idx = gbase + m0 + tid - 1;
        srp[tid] = rp3[idx] + part[idx >> 8];
    }
    __syncthreads();
    const int base = srp[0];
    const int total = srp[16] - base;
    const bool staged = total <= CAP;
    if (staged) {
        for (int i = tid; i < total; i += 256) sidx[i] = csr_src[base + i];
    }
    __syncthreads();

    const int rr = tid >> 4;
    const int cc = tid & 15;
    const int beg = srp[rr];
    const int deg = srp[rr + 1] - beg;
    const int begl = beg - base;
    float a[8], g[8];
#pragma unroll
    for (int v = 0; v < 8; ++v) { a[v] = 0.f; g[v] = 0.f; }
    const unsigned short* col = hl2 + cc * 8;
    auto run = [&](auto IDX) {
        int j = 0;
        for (; j + 7 < deg; j += 8) {
            int s0 = IDX(j),     s1 = IDX(j + 1), s2 = IDX(j + 2), s3 = IDX(j + 3);
            int s4 = IDX(j + 4), s5 = IDX(j + 5), s6 = IDX(j + 6), s7 = IDX(j + 7);
            uint4 v0 = *(const uint4*)(col + (size_t)s0 * K);
            uint4 v1 = *(const uint4*)(col + (size_t)s1 * K);
            uint4 v2 = *(const uint4*)(col + (size_t)s2 * K);
            uint4 v3 = *(const uint4*)(col + (size_t)s3 * K);
            uint4 v4 = *(const uint4*)(col + (size_t)s4 * K);
            uint4 v5 = *(const uint4*)(col + (size_t)s5 * K);
            uint4 v6 = *(const uint4*)(col + (size_t)s6 * K);
            uint4 v7 = *(const uint4*)(col + (size_t)s7 * K);
            acc8(a, v0); acc8(g, v1); acc8(a, v2); acc8(g, v3);
            acc8(a, v4); acc8(g, v5); acc8(a, v6); acc8(g, v7);
        }
        for (; j + 1 < deg; j += 2) {
            int s0 = IDX(j), s1 = IDX(j + 1);
            uint4 v0 = *(const uint4*)(col + (size_t)s0 * K);
            uint4 v1 = *(const uint4*)(col + (size_t)s1 * K);
            acc8(a, v0); acc8(g, v1);
        }
        if (j < deg) {
            uint4 v0 = *(const uint4*)(col + (size_t)IDX(j) * K);
            acc8(a, v0);
        }
    };
    if (staged) run([&](int j) { return sidx[begl + j]; });
    else        run([&](int j) { return csr_src[beg + j]; });

    const float inv = 1.0f / fmaxf((float)deg, 1.0f);
    const size_t ro = (size_t)(m0 + rr) * K + cc * 8;
    uint4 hv = *(const uint4*)(hr2 + ro);
    uint4 bv = *(const uint4*)(bb + cc * 8);
    float h8[8], b8[8];
    h8[0] = bfbits2f(hv.x & 0xffffu); h8[1] = bfbits2f(hv.x >> 16);
    h8[2] = bfbits2f(hv.y & 0xffffu); h8[3] = bfbits2f(hv.y >> 16);
    h8[4] = bfbits2f(hv.z & 0xffffu); h8[5] = bfbits2f(hv.z >> 16);
    h8[6] = bfbits2f(hv.w & 0xffffu); h8[7] = bfbits2f(hv.w >> 16);
    b8[0] = bfbits2f(bv.x & 0xffffu); b8[1] = bfbits2f(bv.x >> 16);
    b8[2] = bfbits2f(bv.y & 0xffffu); b8[3] = bfbits2f(bv.y >> 16);
    b8[4] = bfbits2f(bv.z & 0xffffu); b8[5] = bfbits2f(bv.z >> 16);
    b8[6] = bfbits2f(bv.w & 0xffffu); b8[7] = bfbits2f(bv.w >> 16);
    float o8[8];
#pragma unroll
    for (int v = 0; v < 8; ++v) {
        float m = (a[v] + g[v]) * inv + b8[v] + h8[v];
        o8[v] = m > 0.f ? m : 0.f;
    }
    if (flags[0]) {
        float* op = (float*)out + ro;
        float4 o0 = { o8[0], o8[1], o8[2], o8[3] };
        float4 o1 = { o8[4], o8[5], o8[6], o8[7] };
        *(float4*)op = o0;
        *(float4*)(op + 4) = o1;
    } else {
        short8 t8;
#pragma unroll
        for (int v = 0; v < 8; ++v) t8[v] = (short)f2bfbits(o8[v]);
        *(short8*)((unsigned short*)out + ro) = t8;
    }
}

// ---------------- orchestration ----------------
extern "C" void kernel_launch(void* const* d_in, const int* in_sizes, int n_in,
                              void* d_out, int out_size, void* d_ws, size_t ws_size,
                              hipStream_t stream) {
    const void* x  = d_in[0];
    const int* e[3] = { (const int*)d_in[1], (const int*)d_in[2], (const int*)d_in[3] };

    char* ws = (char*)d_ws;
    int* flags = (int*)ws;                                    // @0
    unsigned short* wt = (unsigned short*)(ws + 1024);        // 525,568 B -> 526,592
    unsigned short* bb0 = wt + 262144;
    unsigned short* bb1 = wt + 262400;
    unsigned short* bb2 = wt + 262656;
    int* rp3    = (int*)(ws + 526592);                        // 150,000 ints -> 1,126,592
    int* ticket = (int*)(ws + 1126592);                       // 1 int -> 1,126,596
    int* part   = (int*)(ws + 1126596);                       // 586 ints -> 1,128,940
    int* csr    = (int*)(ws + 1128960);                       // 3.2 MB -> 4,328,960
    unsigned short* hA = (unsigned short*)(ws + 4328960);     // 25.6 MB -> 29,928,960
    unsigned short* hB = (unsigned short*)(ws + 29928960);    // 25.6 MB -> 55,528,960 (55.5 MB, r4-proven)
    unsigned short* xb  = hB;                 // overlay: dies when L1 fused writes hB
    unsigned short* hl2 = hA;                 // overlay: hA dead after L1 fused reads it
    unsigned short* hr2 = hA + (size_t)N_NODES * 128;

    // 1) zero counts + ticket (contiguous)
    hipMemsetAsync(rp3, 0, 600004, stream);
    // 2) detect-local prep + cvt + count3
    mega1<<<16653, 256, 0, stream>>>(d_in[4], d_in[6], d_in[7], d_in[9],
                                     d_in[10], d_in[12], d_in[5], d_in[8], d_in[11],
                                     wt, x, xb, e[0], e[1], e[2], rp3, flags);
    // 3) two-level scan in one launch
    scan12<<<NB3, 256, 0, stream>>>(rp3, part, ticket);
    // 4) fill graph0
    fill_k<<<EG, 256, 0, stream>>>(e[0], rp3, part, csr, 0, flags);
    // 5) layer 0: xb[.,128] -> hA[.,256]
    sage_fused<128><<<MG, 256, 0, stream>>>(xb, rp3, part, csr, 0, 0,
                                            wt, wt + 32768, bb0, hA);
    // 6) fill graph1 (csr reuse — L0 done reading)
    fill_k<<<EG, 256, 0, stream>>>(e[1], rp3, part, csr, 1, flags);
    // 7) layer 1: hA[.,256] -> hB[.,256] (clobbers xb — dead)
    sage_fused<256><<<MG, 256, 0, stream>>>(hA, rp3, part, csr, N_NODES, N_EDGES,
                                            wt + 65536, wt + 131072, bb1, hB);
    // 8) L2 GEMM pair + fill graph2 merged (independent work)
    gemm_fill<<<2 * MG, 256, 0, stream>>>(hB, wt + 196608, hl2, hr2,
                                          e[2], rp3, part, csr, flags);
    // 9) L2 aggregate + epilogue -> d_out
    agg2<<<MG, 256, 0, stream>>>(hl2, hr2, rp3, part, csr, bb2, d_out, flags);
}